// Round 1
// baseline (559.952 us; speedup 1.0000x reference)
//
#include <hip/hip_runtime.h>
#include <math.h>

#define BATCH 16
#define NHEAD 32
#define HDIM 128
#define HIDDEN 4096
#define BS 16
#define MB 128
#define EPS 1e-6f
#define NWORK 8   // 8 half-wave workers per 256-thread block

// ---------------- RMSNorm: q = x * rsqrt(mean(x^2)+eps) * w ----------------
__global__ __launch_bounds__(256) void rmsnorm_kernel(const float* __restrict__ x,
                                                      const float* __restrict__ w,
                                                      float* __restrict__ q) {
    int b = blockIdx.x;
    int tid = threadIdx.x;
    const float4* xr = (const float4*)(x + (size_t)b * HIDDEN);
    float4 xs[4];
    float ss = 0.f;
#pragma unroll
    for (int i = 0; i < 4; i++) {
        float4 v = xr[tid + i * 256];
        xs[i] = v;
        ss += v.x * v.x + v.y * v.y + v.z * v.z + v.w * v.w;
    }
    // wave64 reduce
#pragma unroll
    for (int m = 32; m >= 1; m >>= 1) ss += __shfl_xor(ss, m, 64);
    __shared__ float red[4];
    int wave = tid >> 6;
    if ((tid & 63) == 0) red[wave] = ss;
    __syncthreads();
    float tot = red[0] + red[1] + red[2] + red[3];
    float rstd = rsqrtf(tot * (1.0f / HIDDEN) + EPS);

    const float4* wr = (const float4*)w;
    float4* qr = (float4*)(q + (size_t)b * HIDDEN);
#pragma unroll
    for (int i = 0; i < 4; i++) {
        float4 v = xs[i];
        float4 ww = wr[tid + i * 256];
        float4 o;
        o.x = v.x * rstd * ww.x;
        o.y = v.y * rstd * ww.y;
        o.z = v.z * rstd * ww.z;
        o.w = v.w * rstd * ww.w;
        qr[tid + i * 256] = o;
    }
}

// ---------------- Paged attention decode, one block per (b,h) ----------------
__global__ __launch_bounds__(256) void attn_kernel(const float* __restrict__ q,
                                                   const float* __restrict__ kc,
                                                   const float* __restrict__ vc,
                                                   const int* __restrict__ bt,
                                                   const int* __restrict__ cl,
                                                   const float* __restrict__ resid,
                                                   float* __restrict__ out) {
    const int h = blockIdx.x;
    const int b = blockIdx.y;
    const int tid = threadIdx.x;
    const int w = tid >> 5;     // worker id 0..7 (half-wave)
    const int lane = tid & 31;  // lane within half-wave

    __shared__ int s_bt[MB];
    __shared__ float s_m[NWORK];
    __shared__ float s_l[NWORK];
    __shared__ float s_acc[NWORK][HDIM];

    if (tid < MB) s_bt[tid] = bt[b * MB + tid];
    const int L = cl[b];
    // q fragment for this head: lane holds dims 4*lane..4*lane+3
    float4 q4 = *(const float4*)(q + (size_t)b * HIDDEN + h * HDIM + 4 * lane);
    __syncthreads();

    const float scale = 0.08838834764831845f;  // 1/sqrt(128)
    float m = -INFINITY;
    float l = 0.f;
    float4 acc = make_float4(0.f, 0.f, 0.f, 0.f);

    for (int s = w; s < L; s += NWORK) {
        int blk = s_bt[s >> 4];
        size_t off = ((((size_t)blk * BS + (s & 15)) * NHEAD + h) * HDIM) + 4 * lane;
        float4 k4 = *(const float4*)(kc + off);
        float4 v4 = *(const float4*)(vc + off);
        float dot = k4.x * q4.x + k4.y * q4.y + k4.z * q4.z + k4.w * q4.w;
        // reduce across the 32-lane half (xor masks <32 stay within the half)
#pragma unroll
        for (int msk = 16; msk >= 1; msk >>= 1) dot += __shfl_xor(dot, msk, 64);
        float score = dot * scale;
        float mn = fmaxf(m, score);
        float alpha = __expf(m - mn);
        float p = __expf(score - mn);
        l = l * alpha + p;
        acc.x = acc.x * alpha + p * v4.x;
        acc.y = acc.y * alpha + p * v4.y;
        acc.z = acc.z * alpha + p * v4.z;
        acc.w = acc.w * alpha + p * v4.w;
        m = mn;
    }

    *((float4*)&s_acc[w][4 * lane]) = acc;
    if (lane == 0) {
        s_m[w] = m;
        s_l[w] = l;
    }
    __syncthreads();

    if (tid < HDIM) {
        float M = -INFINITY;
#pragma unroll
        for (int i = 0; i < NWORK; i++) M = fmaxf(M, s_m[i]);
        float Ls = 0.f, A = 0.f;
#pragma unroll
        for (int i = 0; i < NWORK; i++) {
            float sc = __expf(s_m[i] - M);  // -inf -> 0 for empty workers
            Ls += s_l[i] * sc;
            A += s_acc[i][tid] * sc;
        }
        size_t oi = (size_t)b * HIDDEN + h * HDIM + tid;
        out[oi] = resid[oi] + A / Ls;
    }
}

extern "C" void kernel_launch(void* const* d_in, const int* in_sizes, int n_in,
                              void* d_out, int out_size, void* d_ws, size_t ws_size,
                              hipStream_t stream) {
    const float* hs = (const float*)d_in[0];
    const float* kc = (const float*)d_in[1];
    const float* vc = (const float*)d_in[2];
    const int* bt = (const int*)d_in[3];
    const int* cl = (const int*)d_in[4];
    const float* rw = (const float*)d_in[5];
    float* out = (float*)d_out;
    float* q = (float*)d_ws;  // B*HIDDEN floats = 256 KB scratch

    rmsnorm_kernel<<<BATCH, 256, 0, stream>>>(hs, rw, q);
    attn_kernel<<<dim3(NHEAD, BATCH), 256, 0, stream>>>(q, kc, vc, bt, cl, hs, out);
}

// Round 2
// 496.064 us; speedup vs baseline: 1.1288x; 1.1288x over previous
//
#include <hip/hip_runtime.h>
#include <math.h>

#define BATCH 16
#define NHEAD 32
#define HDIM 128
#define HIDDEN 4096
#define BS 16
#define MB 128
#define EPS 1e-6f
#define NWORK 8   // 8 half-wave workers per 256-thread block
#define SPLIT 8   // flash-decoding context splits per (b,h)

// ws layout (floats):
//   q:    [B][HIDDEN]                 at 0
//   m:    [B][H][SPLIT]               at Q_OFF
//   l:    [B][H][SPLIT]               at L_OFF
//   acc:  [B][H][SPLIT][HDIM]         at A_OFF
#define Q_FLOATS (BATCH * HIDDEN)
#define M_OFF Q_FLOATS
#define L_OFF (M_OFF + BATCH * NHEAD * SPLIT)
#define A_OFF (L_OFF + BATCH * NHEAD * SPLIT)

// ---------------- RMSNorm: q = x * rsqrt(mean(x^2)+eps) * w ----------------
__global__ __launch_bounds__(256) void rmsnorm_kernel(const float* __restrict__ x,
                                                      const float* __restrict__ w,
                                                      float* __restrict__ q) {
    int b = blockIdx.x;
    int tid = threadIdx.x;
    const float4* xr = (const float4*)(x + (size_t)b * HIDDEN);
    float4 xs[4];
    float ss = 0.f;
#pragma unroll
    for (int i = 0; i < 4; i++) {
        float4 v = xr[tid + i * 256];
        xs[i] = v;
        ss += v.x * v.x + v.y * v.y + v.z * v.z + v.w * v.w;
    }
#pragma unroll
    for (int m = 32; m >= 1; m >>= 1) ss += __shfl_xor(ss, m, 64);
    __shared__ float red[4];
    int wave = tid >> 6;
    if ((tid & 63) == 0) red[wave] = ss;
    __syncthreads();
    float tot = red[0] + red[1] + red[2] + red[3];
    float rstd = rsqrtf(tot * (1.0f / HIDDEN) + EPS);

    const float4* wr = (const float4*)w;
    float4* qr = (float4*)(q + (size_t)b * HIDDEN);
#pragma unroll
    for (int i = 0; i < 4; i++) {
        float4 v = xs[i];
        float4 ww = wr[tid + i * 256];
        float4 o;
        o.x = v.x * rstd * ww.x;
        o.y = v.y * rstd * ww.y;
        o.z = v.z * rstd * ww.z;
        o.w = v.w * rstd * ww.w;
        qr[tid + i * 256] = o;
    }
}

// ------------- Paged attention partial: one block per (b,h,split) -------------
__global__ __launch_bounds__(256) void attn_partial_kernel(const float* __restrict__ ws,
                                                           const float* __restrict__ kc,
                                                           const float* __restrict__ vc,
                                                           const int* __restrict__ bt,
                                                           const int* __restrict__ cl,
                                                           float* __restrict__ pm,
                                                           float* __restrict__ pl,
                                                           float* __restrict__ pacc) {
    const int h = blockIdx.x;
    const int b = blockIdx.y;
    const int si = blockIdx.z;
    const int tid = threadIdx.x;
    const int w = tid >> 5;     // worker 0..7 (half-wave)
    const int lane = tid & 31;

    __shared__ int s_bt[MB];
    __shared__ float s_m[NWORK];
    __shared__ float s_l[NWORK];
    __shared__ float s_acc[NWORK][HDIM];

    const int L = cl[b];
    const int chunk = (L + SPLIT - 1) / SPLIT;
    const int s0 = si * chunk;
    const int s1 = min(s0 + chunk, L);

    if (tid < MB) s_bt[tid] = bt[b * MB + tid];
    float4 q4 = *(const float4*)(ws + (size_t)b * HIDDEN + h * HDIM + 4 * lane);
    __syncthreads();

    const float scale = 0.08838834764831845f;  // 1/sqrt(128)
    float m = -INFINITY;
    float l = 0.f;
    float4 acc = make_float4(0.f, 0.f, 0.f, 0.f);

    int s = s0 + w;
    // unroll-2: two independent K/V loads in flight, one rescale per pair
    for (; s + NWORK < s1; s += 2 * NWORK) {
        int sB = s + NWORK;
        size_t offA = ((((size_t)s_bt[s >> 4] * BS + (s & 15)) * NHEAD + h) * HDIM) + 4 * lane;
        size_t offB = ((((size_t)s_bt[sB >> 4] * BS + (sB & 15)) * NHEAD + h) * HDIM) + 4 * lane;
        float4 kA = *(const float4*)(kc + offA);
        float4 kB = *(const float4*)(kc + offB);
        float4 vA = *(const float4*)(vc + offA);
        float4 vB = *(const float4*)(vc + offB);
        float dA = kA.x * q4.x + kA.y * q4.y + kA.z * q4.z + kA.w * q4.w;
        float dB = kB.x * q4.x + kB.y * q4.y + kB.z * q4.z + kB.w * q4.w;
#pragma unroll
        for (int msk = 16; msk >= 1; msk >>= 1) {
            dA += __shfl_xor(dA, msk, 64);
            dB += __shfl_xor(dB, msk, 64);
        }
        float scA = dA * scale, scB = dB * scale;
        float mn = fmaxf(m, fmaxf(scA, scB));
        float alpha = __expf(m - mn);
        float p0 = __expf(scA - mn);
        float p1 = __expf(scB - mn);
        l = l * alpha + p0 + p1;
        acc.x = acc.x * alpha + p0 * vA.x + p1 * vB.x;
        acc.y = acc.y * alpha + p0 * vA.y + p1 * vB.y;
        acc.z = acc.z * alpha + p0 * vA.z + p1 * vB.z;
        acc.w = acc.w * alpha + p0 * vA.w + p1 * vB.w;
        m = mn;
    }
    for (; s < s1; s += NWORK) {
        size_t off = ((((size_t)s_bt[s >> 4] * BS + (s & 15)) * NHEAD + h) * HDIM) + 4 * lane;
        float4 k4 = *(const float4*)(kc + off);
        float4 v4 = *(const float4*)(vc + off);
        float dot = k4.x * q4.x + k4.y * q4.y + k4.z * q4.z + k4.w * q4.w;
#pragma unroll
        for (int msk = 16; msk >= 1; msk >>= 1) dot += __shfl_xor(dot, msk, 64);
        float score = dot * scale;
        float mn = fmaxf(m, score);
        float alpha = __expf(m - mn);
        float p = __expf(score - mn);
        l = l * alpha + p;
        acc.x = acc.x * alpha + p * v4.x;
        acc.y = acc.y * alpha + p * v4.y;
        acc.z = acc.z * alpha + p * v4.z;
        acc.w = acc.w * alpha + p * v4.w;
        m = mn;
    }

    *((float4*)&s_acc[w][4 * lane]) = acc;
    if (lane == 0) {
        s_m[w] = m;
        s_l[w] = l;
    }
    __syncthreads();

    // block combine -> partial for this split
    if (tid < HDIM) {
        float M = -INFINITY;
#pragma unroll
        for (int i = 0; i < NWORK; i++) M = fmaxf(M, s_m[i]);
        size_t pbase = ((size_t)(b * NHEAD + h) * SPLIT + si);
        if (M == -INFINITY) {  // empty chunk: write neutral partial
            if (tid == 0) { pm[pbase] = -INFINITY; pl[pbase] = 0.f; }
            pacc[pbase * HDIM + tid] = 0.f;
        } else {
            float Ls = 0.f, A = 0.f;
#pragma unroll
            for (int i = 0; i < NWORK; i++) {
                float sc = __expf(s_m[i] - M);  // -inf worker -> 0
                Ls += s_l[i] * sc;
                A += s_acc[i][tid] * sc;
            }
            if (tid == 0) { pm[pbase] = M; pl[pbase] = Ls; }
            pacc[pbase * HDIM + tid] = A;
        }
    }
}

// ---------------- Combine splits + residual ----------------
__global__ __launch_bounds__(128) void attn_combine_kernel(const float* __restrict__ pm,
                                                           const float* __restrict__ pl,
                                                           const float* __restrict__ pacc,
                                                           const float* __restrict__ resid,
                                                           float* __restrict__ out) {
    const int h = blockIdx.x;
    const int b = blockIdx.y;
    const int tid = threadIdx.x;
    size_t pbase = (size_t)(b * NHEAD + h) * SPLIT;

    float M = -INFINITY;
#pragma unroll
    for (int i = 0; i < SPLIT; i++) M = fmaxf(M, pm[pbase + i]);
    float Ls = 0.f, A = 0.f;
#pragma unroll
    for (int i = 0; i < SPLIT; i++) {
        float sc = __expf(pm[pbase + i] - M);  // empty split (m=-inf) -> 0
        Ls += pl[pbase + i] * sc;
        A += pacc[(pbase + i) * HDIM + tid] * sc;
    }
    size_t oi = (size_t)b * HIDDEN + h * HDIM + tid;
    out[oi] = resid[oi] + A / Ls;
}

extern "C" void kernel_launch(void* const* d_in, const int* in_sizes, int n_in,
                              void* d_out, int out_size, void* d_ws, size_t ws_size,
                              hipStream_t stream) {
    const float* hs = (const float*)d_in[0];
    const float* kc = (const float*)d_in[1];
    const float* vc = (const float*)d_in[2];
    const int* bt = (const int*)d_in[3];
    const int* cl = (const int*)d_in[4];
    const float* rw = (const float*)d_in[5];
    float* out = (float*)d_out;
    float* ws = (float*)d_ws;
    float* q = ws;
    float* pm = ws + M_OFF;
    float* pl = ws + L_OFF;
    float* pacc = ws + A_OFF;

    rmsnorm_kernel<<<BATCH, 256, 0, stream>>>(hs, rw, q);
    attn_partial_kernel<<<dim3(NHEAD, BATCH, SPLIT), 256, 0, stream>>>(q, kc, vc, bt, cl,
                                                                       pm, pl, pacc);
    attn_combine_kernel<<<dim3(NHEAD, BATCH), 128, 0, stream>>>(pm, pl, pacc, hs, out);
}